// Round 10
// baseline (80.374 us; speedup 1.0000x reference)
//
#include <hip/hip_runtime.h>
#include <math.h>

#define B_DIM 256
#define M_DIM 256
#define C_DIM 1024
#define C4    256            // C/4 float4 per row
#define UM_OFF (B_DIM * C_DIM)                       // 262144 floats
#define KL_OFF (UM_OFF + B_DIM * M_DIM * C_DIM)      // 67371008 floats
#define SCALE  0.03125f      // 1/sqrt(1024)

typedef float nfloat4 __attribute__((ext_vector_type(4)));

__device__ __forceinline__ void nt_store4(float4 v, float4* p) {
    nfloat4 n = {v.x, v.y, v.z, v.w};
    __builtin_nontemporal_store(n, (nfloat4*)p);
}
__device__ __forceinline__ float dot4(float4 a, float4 b) {
    return a.x*b.x + a.y*b.y + a.z*b.z + a.w*b.w;
}

// ---------------- K1: per-batch prefix + z + kl (no um traffic). ----------
// One block per batch b; 512 threads = 8 waves.
__global__ __launch_bounds__(512) void tm_pre(const float* __restrict__ x,
                                              const float* __restrict__ mem,
                                              float* __restrict__ out,
                                              int* __restrict__ idx_ws) {
    const int b = blockIdx.x;
    const int t = threadIdx.x;
    const int lane = t & 63;
    const int wv = t >> 6;     // 0..7
    const int tc = t & 255;    // column float4 id
    const int h  = t >> 8;     // 0/1

    __shared__ float4 s_x[C4];        // 4 KB
    __shared__ float4 s_zp[C4];       // 4 KB
    __shared__ float  s_sims[M_DIM];  // 1 KB
    __shared__ float  s_attn[M_DIM];  // 1 KB
    __shared__ float  s_w[8];
    __shared__ float  s_av[8];
    __shared__ int    s_ai[8];
    __shared__ int    s_idxs;

    const float4* mem4 = (const float4*)mem;

    float4 xv = make_float4(0.f, 0.f, 0.f, 0.f);
    if (h == 0) {
        xv = ((const float4*)(x + (size_t)b * C_DIM))[tc];
        s_x[tc] = xv;
    }
    __syncthreads();

    // n2 = ||x||^2
    float n2;
    {
        float p = (h == 0) ? dot4(xv, xv) : 0.f;
        #pragma unroll
        for (int off = 32; off; off >>= 1) p += __shfl_xor(p, off, 64);
        if (lane == 0) s_w[wv] = p;
        __syncthreads();
        n2 = s_w[0]+s_w[1]+s_w[2]+s_w[3]+s_w[4]+s_w[5]+s_w[6]+s_w[7];
        __syncthreads();
    }

    // sims: wave wv owns m in [wv*32, wv*32+32)
    {
        const float4 xr0 = s_x[lane];
        const float4 xr1 = s_x[lane + 64];
        const float4 xr2 = s_x[lane + 128];
        const float4 xr3 = s_x[lane + 192];
        #pragma unroll 4
        for (int i = 0; i < 32; ++i) {
            const int m = (wv << 5) | i;
            const float4* mr = mem4 + (m << 8);
            float acc = dot4(mr[lane],     xr0) + dot4(mr[lane+64],  xr1)
                      + dot4(mr[lane+128], xr2) + dot4(mr[lane+192], xr3);
            #pragma unroll
            for (int off = 32; off; off >>= 1) acc += __shfl_xor(acc, off, 64);
            if (lane == 0) s_sims[m] = acc;
        }
    }
    __syncthreads();

    // argmax (first-max tie-break, like np.argmax)
    {
        float av = -INFINITY; int ai = 0x7fffffff;
        if (h == 0) { av = s_sims[tc]; ai = tc; }
        #pragma unroll
        for (int off = 32; off; off >>= 1) {
            float ov = __shfl_xor(av, off, 64);
            int   oi = __shfl_xor(ai, off, 64);
            if (ov > av || (ov == av && oi < ai)) { av = ov; ai = oi; }
        }
        if (lane == 0) { s_av[wv] = av; s_ai[wv] = ai; }
        __syncthreads();
        if (t == 0) {
            float bv = s_av[0]; int bi = s_ai[0];
            #pragma unroll
            for (int w = 1; w < 4; ++w) {
                float v2 = s_av[w]; int i2 = s_ai[w];
                if (v2 > bv || (v2 == bv && i2 < bi)) { bv = v2; bi = i2; }
            }
            s_idxs = bi;
            idx_ws[b] = bi;      // visible to tm_fill via dispatch ordering
        }
        __syncthreads();
    }
    const int idx = s_idxs;

    // scores + softmax (thread tc of half 0 owns slot m = tc)
    float sc = -INFINITY;
    if (h == 0)
        sc = (tc == idx) ? (0.9f * s_sims[idx] + 0.1f * n2) * SCALE
                         : s_sims[tc] * SCALE;
    float mx;
    {
        float v = sc;
        #pragma unroll
        for (int off = 32; off; off >>= 1) v = fmaxf(v, __shfl_xor(v, off, 64));
        if (lane == 0) s_w[wv] = v;
        __syncthreads();
        mx = fmaxf(fmaxf(fmaxf(s_w[0], s_w[1]), fmaxf(s_w[2], s_w[3])),
                   fmaxf(fmaxf(s_w[4], s_w[5]), fmaxf(s_w[6], s_w[7])));
        __syncthreads();
    }
    float e = (h == 0) ? expf(sc - mx) : 0.f;
    float esum;
    {
        float v = e;
        #pragma unroll
        for (int off = 32; off; off >>= 1) v += __shfl_xor(v, off, 64);
        if (lane == 0) s_w[wv] = v;
        __syncthreads();
        esum = s_w[0]+s_w[1]+s_w[2]+s_w[3]+s_w[4]+s_w[5]+s_w[6]+s_w[7];
        __syncthreads();
    }
    if (h == 0) s_attn[tc] = e / esum;

    // d = x - mem[idx], dw = ||d||^2  (reduction also publishes s_attn)
    float4 d = make_float4(0.f, 0.f, 0.f, 0.f);
    float dw;
    {
        float dd = 0.f;
        if (h == 0) {
            float4 sl = mem4[(idx << 8) + tc];
            d = make_float4(xv.x - sl.x, xv.y - sl.y, xv.z - sl.z, xv.w - sl.w);
            dd = dot4(d, d);
        }
        float v = dd;
        #pragma unroll
        for (int off = 32; off; off >>= 1) v += __shfl_xor(v, off, 64);
        if (lane == 0) s_w[wv] = v;
        __syncthreads();
        dw = s_w[0]+s_w[1]+s_w[2]+s_w[3]+s_w[4]+s_w[5]+s_w[6]+s_w[7];
        __syncthreads();
    }

    // z = attn @ mem (m split across halves)
    float4 z = make_float4(0.f, 0.f, 0.f, 0.f);
    #pragma unroll 4
    for (int i = 0; i < 128; ++i) {
        const int m = (h << 7) + i;
        float4 v = mem4[(m << 8) + tc];
        const float a = s_attn[m];
        z.x = fmaf(a, v.x, z.x);
        z.y = fmaf(a, v.y, z.y);
        z.z = fmaf(a, v.z, z.z);
        z.w = fmaf(a, v.w, z.w);
    }
    if (h == 1) s_zp[tc] = z;
    __syncthreads();
    float drp = 0.f;
    if (h == 0) {
        float4 zo = s_zp[tc];
        z.x += zo.x; z.y += zo.y; z.z += zo.z; z.w += zo.w;
        const float aidx = s_attn[idx] * 0.1f;
        z.x = fmaf(aidx, d.x, z.x);
        z.y = fmaf(aidx, d.y, z.y);
        z.z = fmaf(aidx, d.z, z.z);
        z.w = fmaf(aidx, d.w, z.w);
        float e0 = z.x - xv.x, e1 = z.y - xv.y, e2 = z.z - xv.z, e3 = z.w - xv.w;
        drp = e0*e0 + e1*e1 + e2*e2 + e3*e3;
        ((float4*)out)[(size_t)b * C4 + tc] = z;
    }
    {
        float v = drp;
        #pragma unroll
        for (int off = 32; off; off >>= 1) v += __shfl_xor(v, off, 64);
        if (lane == 0) s_w[wv] = v;
        __syncthreads();
        if (t == 0) out[KL_OFF + b] = 0.5f * (dw + s_w[0]+s_w[1]+s_w[2]+s_w[3]
                                                 + s_w[4]+s_w[5]+s_w[6]+s_w[7]);
    }
}

// ---------------- K2: fill-geometry stream. 2048 blocks x 256 thr (8/CU).
// Block j owns rows [32j, 32j+32) = contiguous 128 KB; single batch per block.
__global__ __launch_bounds__(256) void tm_fill(const float* __restrict__ x,
                                               const float* __restrict__ mem,
                                               const int* __restrict__ idx_ws,
                                               float* __restrict__ out_um) {
    const int j = blockIdx.x;      // 0..2047
    const int t = threadIdx.x;     // column float4 id
    const int b  = j >> 3;         // 8 blocks per batch
    const int m0 = (j & 7) << 5;   // 0,32,...,224

    const float4* mem4 = (const float4*)mem;
    float4* dst = (float4*)out_um + (((size_t)b << 8) + m0 << 8) + t;

    const int idx = idx_ws[b];
    const int li = idx - m0;                       // local blend row if in [0,32)
    float4 xv = make_float4(0.f, 0.f, 0.f, 0.f);
    if (li >= 0 && li < 32)
        xv = ((const float4*)(x + (size_t)b * C_DIM))[t];

    #pragma unroll 8
    for (int i = 0; i < 32; ++i) {
        float4 v = mem4[((m0 + i) << 8) + t];
        if (i == li) {
            v.x = 0.9f*v.x + 0.1f*xv.x;
            v.y = 0.9f*v.y + 0.1f*xv.y;
            v.z = 0.9f*v.z + 0.1f*xv.z;
            v.w = 0.9f*v.w + 0.1f*xv.w;
        }
        nt_store4(v, dst + (i << 8));
    }
}

extern "C" void kernel_launch(void* const* d_in, const int* in_sizes, int n_in,
                              void* d_out, int out_size, void* d_ws, size_t ws_size,
                              hipStream_t stream) {
    const float* x   = (const float*)d_in[0];   // input_encoded [B, C]
    const float* mem = (const float*)d_in[1];   // memory_mean  [M, C]
    float* out = (float*)d_out;
    int* idx_ws = (int*)d_ws;

    tm_pre<<<dim3(B_DIM), dim3(512), 0, stream>>>(x, mem, out, idx_ws);
    tm_fill<<<dim3(2048), dim3(256), 0, stream>>>(x, mem, idx_ws, out + UM_OFF);
}

// Round 11
// 74.203 us; speedup vs baseline: 1.0832x; 1.0832x over previous
//
#include <hip/hip_runtime.h>
#include <math.h>

#define B_DIM 256
#define M_DIM 256
#define C_DIM 1024
#define C4    256            // C/4 float4 per row
#define UM_OFF (B_DIM * C_DIM)                       // 262144 floats
#define KL_OFF (UM_OFF + B_DIM * M_DIM * C_DIM)      // 67371008 floats
#define SCALE  0.03125f      // 1/sqrt(1024)

typedef float nfloat4 __attribute__((ext_vector_type(4)));

__device__ __forceinline__ void nt_store4(float4 v, float4* p) {
    nfloat4 n = {v.x, v.y, v.z, v.w};
    __builtin_nontemporal_store(n, (nfloat4*)p);
}
__device__ __forceinline__ float dot4(float4 a, float4 b) {
    return a.x*b.x + a.y*b.y + a.z*b.z + a.w*b.w;
}
__device__ __forceinline__ float wsum(float v) {
    #pragma unroll
    for (int off = 32; off; off >>= 1) v += __shfl_xor(v, off, 64);
    return v;
}
__device__ __forceinline__ float wmax(float v) {
    #pragma unroll
    for (int off = 32; off; off >>= 1) v = fmaxf(v, __shfl_xor(v, off, 64));
    return v;
}
__device__ __forceinline__ float4 blend9(float4 v, float4 xr) {
    return make_float4(0.9f*v.x + 0.1f*xr.x, 0.9f*v.y + 0.1f*xr.y,
                       0.9f*v.z + 0.1f*xr.z, 0.9f*v.w + 0.1f*xr.w);
}

// One block per batch b. 1024 threads = 16 waves. 4 barriers total.
__global__ __launch_bounds__(1024) void tm_v11(const float* __restrict__ x,
                                               const float* __restrict__ mem,
                                               float* __restrict__ out) {
    const int b = blockIdx.x;
    const int t = threadIdx.x;
    const int lane = t & 63;
    const int wv = t >> 6;      // 0..15
    const int tc = t & 255;     // column float4 id
    const int q  = t >> 8;      // 0..3 (m-quarter)

    __shared__ float4 s_x[C4];        // 4 KB
    __shared__ float4 s_zp[3][C4];    // 12 KB
    __shared__ float  s_sims[M_DIM];  // 1 KB
    __shared__ float  s_w[4];

    const float4* mem4 = (const float4*)mem;

    // ---- P1: stage x ----
    float4 xv = make_float4(0.f, 0.f, 0.f, 0.f);
    if (q == 0) {
        xv = ((const float4*)(x + (size_t)b * C_DIM))[tc];
        s_x[tc] = xv;
    }
    __syncthreads();                                   // barrier 1

    // ---- P2: sims (wave wv owns m = wv*16 .. +15) ----
    {
        const float4 xr0 = s_x[lane];
        const float4 xr1 = s_x[lane + 64];
        const float4 xr2 = s_x[lane + 128];
        const float4 xr3 = s_x[lane + 192];
        #pragma unroll 4
        for (int i = 0; i < 16; ++i) {
            const int m = (wv << 4) | i;
            const float4* mr = mem4 + (m << 8);
            float acc = dot4(mr[lane],     xr0) + dot4(mr[lane+64],  xr1)
                      + dot4(mr[lane+128], xr2) + dot4(mr[lane+192], xr3);
            acc = wsum(acc);
            if (lane == 0) s_sims[m] = acc;
        }
    }
    __syncthreads();                                   // barrier 2

    // ---- P3: per-wave redundant softmax (ZERO barriers; identical in all waves) ----
    const float v0 = s_sims[lane];
    const float v1 = s_sims[lane + 64];
    const float v2 = s_sims[lane + 128];
    const float v3 = s_sims[lane + 192];
    const float4 xa = s_x[lane], xb = s_x[lane + 64];
    const float4 xc = s_x[lane + 128], xd = s_x[lane + 192];
    const float n2 = wsum(dot4(xa,xa) + dot4(xb,xb) + dot4(xc,xc) + dot4(xd,xd));

    // argmax, first-max tie-break (in-lane sequential keeps smallest m on ties)
    float av = v0; int am = lane;
    if (v1 > av) { av = v1; am = lane + 64; }
    if (v2 > av) { av = v2; am = lane + 128; }
    if (v3 > av) { av = v3; am = lane + 192; }
    #pragma unroll
    for (int off = 32; off; off >>= 1) {
        float ov = __shfl_xor(av, off, 64);
        int   oi = __shfl_xor(am, off, 64);
        if (ov > av || (ov == av && oi < am)) { av = ov; am = oi; }
    }
    const int idx = am;          // wave-uniform, identical across waves
    const float fused = 0.9f * av + 0.1f * n2;

    float s0 = ((lane      ) == idx ? fused : v0) * SCALE;
    float s1 = ((lane +  64) == idx ? fused : v1) * SCALE;
    float s2 = ((lane + 128) == idx ? fused : v2) * SCALE;
    float s3 = ((lane + 192) == idx ? fused : v3) * SCALE;
    const float mx = wmax(fmaxf(fmaxf(s0, s1), fmaxf(s2, s3)));
    const float e0 = expf(s0 - mx), e1 = expf(s1 - mx);
    const float e2 = expf(s2 - mx), e3 = expf(s3 - mx);
    const float inv = 1.0f / wsum(e0 + e1 + e2 + e3);
    const float a0 = e0 * inv, a1 = e1 * inv, a2 = e2 * inv, a3 = e3 * inv;

    float aidx;
    if      (idx <  64) aidx = __shfl(a0, idx,       64);
    else if (idx < 128) aidx = __shfl(a1, idx - 64,  64);
    else if (idx < 192) aidx = __shfl(a2, idx - 128, 64);
    else                aidx = __shfl(a3, idx - 192, 64);
    aidx *= 0.1f;

    // dw = ||x - mem[idx]||^2 (wave 0 only; t==0 consumer is in wave 0)
    float dw = 0.f;
    if (wv == 0) {
        const float4* ir = mem4 + (idx << 8);
        float4 q0 = ir[lane], q1 = ir[lane+64], q2 = ir[lane+128], q3 = ir[lane+192];
        float p = 0.f; float4 dq;
        dq = make_float4(xa.x-q0.x, xa.y-q0.y, xa.z-q0.z, xa.w-q0.w); p += dot4(dq,dq);
        dq = make_float4(xb.x-q1.x, xb.y-q1.y, xb.z-q1.z, xb.w-q1.w); p += dot4(dq,dq);
        dq = make_float4(xc.x-q2.x, xc.y-q2.y, xc.z-q2.z, xc.w-q2.w); p += dot4(dq,dq);
        dq = make_float4(xd.x-q3.x, xd.y-q3.y, xd.z-q3.z, xd.w-q3.w); p += dot4(dq,dq);
        dw = wsum(p);
    }

    // ---- P4: z partial (quarter q covers m = q*64 .. +63); attn via shfl ----
    float4 z = make_float4(0.f, 0.f, 0.f, 0.f);
    {
        const float4* zsrc = mem4 + ((q << 6) << 8) + tc;
        auto zrun = [&](float areg) {
            #pragma unroll 4
            for (int i = 0; i < 64; ++i) {
                const float a = __shfl(areg, i, 64);
                float4 v = zsrc[i << 8];
                z.x = fmaf(a, v.x, z.x);
                z.y = fmaf(a, v.y, z.y);
                z.z = fmaf(a, v.z, z.z);
                z.w = fmaf(a, v.w, z.w);
            }
        };
        if      (q == 0) zrun(a0);
        else if (q == 1) zrun(a1);
        else if (q == 2) zrun(a2);
        else             zrun(a3);
    }
    if (q) s_zp[q - 1][tc] = z;
    __syncthreads();                                   // barrier 3
    float drp = 0.f;
    if (q == 0) {
        float4 z1 = s_zp[0][tc], z2 = s_zp[1][tc], z3 = s_zp[2][tc];
        z.x += z1.x + z2.x + z3.x;
        z.y += z1.y + z2.y + z3.y;
        z.z += z1.z + z2.z + z3.z;
        z.w += z1.w + z2.w + z3.w;
        float4 sl = mem4[(idx << 8) + tc];
        float4 d = make_float4(xv.x - sl.x, xv.y - sl.y, xv.z - sl.z, xv.w - sl.w);
        z.x = fmaf(aidx, d.x, z.x);
        z.y = fmaf(aidx, d.y, z.y);
        z.z = fmaf(aidx, d.z, z.z);
        z.w = fmaf(aidx, d.w, z.w);
        float ex = z.x - xv.x, ey = z.y - xv.y, ez = z.z - xv.z, ew = z.w - xv.w;
        drp = ex*ex + ey*ey + ez*ez + ew*ew;
        ((float4*)out)[(size_t)b * C4 + tc] = z;
    }
    {
        float s = wsum(drp);
        if (q == 0 && lane == 0) s_w[wv] = s;          // wv 0..3
    }
    __syncthreads();                                   // barrier 4 (last)
    if (t == 0) out[KL_OFF + b] = 0.5f * (dw + s_w[0] + s_w[1] + s_w[2] + s_w[3]);

    // ---- P5: stream (pure stores, 2x4-row register double-buffer, no barriers) ----
    const int mq = q << 6;
    const float4* src = mem4 + (mq << 8) + tc;
    float4* dst = (float4*)(out + UM_OFF) + ((size_t)b << 16) + (mq << 8) + tc;
    const int lidx = idx - mq;        // blend row within this quarter if in [0,64)
    const float4 xr = s_x[tc];

    float4 A0, A1, A2, A3, B0, B1, B2, B3;
    A0 = src[0 << 8]; A1 = src[1 << 8]; A2 = src[2 << 8]; A3 = src[3 << 8];

    #define STORE_CHUNK(R0, R1, R2, R3, base)                                   \
        { float4 v;                                                             \
          v = ((base)+0 == lidx) ? blend9(R0, xr) : R0; nt_store4(v, dst + (((base)+0) << 8)); \
          v = ((base)+1 == lidx) ? blend9(R1, xr) : R1; nt_store4(v, dst + (((base)+1) << 8)); \
          v = ((base)+2 == lidx) ? blend9(R2, xr) : R2; nt_store4(v, dst + (((base)+2) << 8)); \
          v = ((base)+3 == lidx) ? blend9(R3, xr) : R3; nt_store4(v, dst + (((base)+3) << 8)); }

    #pragma unroll
    for (int k = 0; k < 7; ++k) {
        const int rB = (2*k + 1) << 2;
        const int rA = (2*k) << 2;
        B0 = src[(rB+0) << 8]; B1 = src[(rB+1) << 8];
        B2 = src[(rB+2) << 8]; B3 = src[(rB+3) << 8];
        STORE_CHUNK(A0, A1, A2, A3, rA);
        const int rA2 = (2*k + 2) << 2;
        A0 = src[(rA2+0) << 8]; A1 = src[(rA2+1) << 8];
        A2 = src[(rA2+2) << 8]; A3 = src[(rA2+3) << 8];
        STORE_CHUNK(B0, B1, B2, B3, rB);
    }
    // tail: A holds chunk 14 (rows 56..59); load chunk 15, store both
    B0 = src[60 << 8]; B1 = src[61 << 8]; B2 = src[62 << 8]; B3 = src[63 << 8];
    STORE_CHUNK(A0, A1, A2, A3, 56);
    STORE_CHUNK(B0, B1, B2, B3, 60);
    #undef STORE_CHUNK
}

extern "C" void kernel_launch(void* const* d_in, const int* in_sizes, int n_in,
                              void* d_out, int out_size, void* d_ws, size_t ws_size,
                              hipStream_t stream) {
    const float* x   = (const float*)d_in[0];   // input_encoded [B, C]
    const float* mem = (const float*)d_in[1];   // memory_mean  [M, C]
    float* out = (float*)d_out;

    tm_v11<<<dim3(B_DIM), dim3(1024), 0, stream>>>(x, mem, out);
}

// Round 12
// 67.477 us; speedup vs baseline: 1.1911x; 1.0997x over previous
//
#include <hip/hip_runtime.h>
#include <math.h>

#define B_DIM 256
#define M_DIM 256
#define C_DIM 1024
#define C4    256            // C/4 float4 per row
#define UM_OFF (B_DIM * C_DIM)                       // 262144 floats
#define KL_OFF (UM_OFF + B_DIM * M_DIM * C_DIM)      // 67371008 floats
#define SCALE  0.03125f      // 1/sqrt(1024)

__device__ __forceinline__ float dot4(float4 a, float4 b) {
    return a.x*b.x + a.y*b.y + a.z*b.z + a.w*b.w;
}
__device__ __forceinline__ float wsum(float v) {
    #pragma unroll
    for (int off = 32; off; off >>= 1) v += __shfl_xor(v, off, 64);
    return v;
}
__device__ __forceinline__ float wmax(float v) {
    #pragma unroll
    for (int off = 32; off; off >>= 1) v = fmaxf(v, __shfl_xor(v, off, 64));
    return v;
}
__device__ __forceinline__ float4 blend9(float4 v, float4 xr) {
    return make_float4(0.9f*v.x + 0.1f*xr.x, 0.9f*v.y + 0.1f*xr.y,
                       0.9f*v.z + 0.1f*xr.z, 0.9f*v.w + 0.1f*xr.w);
}

// ---------------- K1: prefix + z + kl. One block per batch, 1024 thr, 4 barriers.
__global__ __launch_bounds__(1024) void tm_pre(const float* __restrict__ x,
                                               const float* __restrict__ mem,
                                               float* __restrict__ out,
                                               int* __restrict__ idx_ws) {
    const int b = blockIdx.x;
    const int t = threadIdx.x;
    const int lane = t & 63;
    const int wv = t >> 6;      // 0..15
    const int tc = t & 255;     // column float4 id
    const int q  = t >> 8;      // 0..3 (m-quarter)

    __shared__ float4 s_x[C4];        // 4 KB
    __shared__ float4 s_zp[3][C4];    // 12 KB
    __shared__ float  s_sims[M_DIM];  // 1 KB
    __shared__ float  s_w[4];

    const float4* mem4 = (const float4*)mem;

    // ---- P1: stage x ----
    float4 xv = make_float4(0.f, 0.f, 0.f, 0.f);
    if (q == 0) {
        xv = ((const float4*)(x + (size_t)b * C_DIM))[tc];
        s_x[tc] = xv;
    }
    __syncthreads();                                   // barrier 1

    // ---- P2: sims (wave wv owns m = wv*16 .. +15) ----
    {
        const float4 xr0 = s_x[lane];
        const float4 xr1 = s_x[lane + 64];
        const float4 xr2 = s_x[lane + 128];
        const float4 xr3 = s_x[lane + 192];
        #pragma unroll 4
        for (int i = 0; i < 16; ++i) {
            const int m = (wv << 4) | i;
            const float4* mr = mem4 + (m << 8);
            float acc = dot4(mr[lane],     xr0) + dot4(mr[lane+64],  xr1)
                      + dot4(mr[lane+128], xr2) + dot4(mr[lane+192], xr3);
            acc = wsum(acc);
            if (lane == 0) s_sims[m] = acc;
        }
    }
    __syncthreads();                                   // barrier 2

    // ---- P3: per-wave redundant softmax (zero barriers) ----
    const float v0 = s_sims[lane];
    const float v1 = s_sims[lane + 64];
    const float v2 = s_sims[lane + 128];
    const float v3 = s_sims[lane + 192];
    const float4 xa = s_x[lane], xb = s_x[lane + 64];
    const float4 xc = s_x[lane + 128], xd = s_x[lane + 192];
    const float n2 = wsum(dot4(xa,xa) + dot4(xb,xb) + dot4(xc,xc) + dot4(xd,xd));

    // argmax, first-max tie-break
    float av = v0; int am = lane;
    if (v1 > av) { av = v1; am = lane + 64; }
    if (v2 > av) { av = v2; am = lane + 128; }
    if (v3 > av) { av = v3; am = lane + 192; }
    #pragma unroll
    for (int off = 32; off; off >>= 1) {
        float ov = __shfl_xor(av, off, 64);
        int   oi = __shfl_xor(am, off, 64);
        if (ov > av || (ov == av && oi < am)) { av = ov; am = oi; }
    }
    const int idx = am;
    if (t == 0) idx_ws[b] = idx;       // visible to tm_stream at kernel boundary
    const float fused = 0.9f * av + 0.1f * n2;

    float s0 = ((lane      ) == idx ? fused : v0) * SCALE;
    float s1 = ((lane +  64) == idx ? fused : v1) * SCALE;
    float s2 = ((lane + 128) == idx ? fused : v2) * SCALE;
    float s3 = ((lane + 192) == idx ? fused : v3) * SCALE;
    const float mx = wmax(fmaxf(fmaxf(s0, s1), fmaxf(s2, s3)));
    const float e0 = expf(s0 - mx), e1 = expf(s1 - mx);
    const float e2 = expf(s2 - mx), e3 = expf(s3 - mx);
    const float inv = 1.0f / wsum(e0 + e1 + e2 + e3);
    const float a0 = e0 * inv, a1 = e1 * inv, a2 = e2 * inv, a3 = e3 * inv;

    float aidx;
    if      (idx <  64) aidx = __shfl(a0, idx,       64);
    else if (idx < 128) aidx = __shfl(a1, idx - 64,  64);
    else if (idx < 192) aidx = __shfl(a2, idx - 128, 64);
    else                aidx = __shfl(a3, idx - 192, 64);
    aidx *= 0.1f;

    // dw = ||x - mem[idx]||^2 (wave 0 only)
    float dw = 0.f;
    if (wv == 0) {
        const float4* ir = mem4 + (idx << 8);
        float4 q0 = ir[lane], q1 = ir[lane+64], q2 = ir[lane+128], q3 = ir[lane+192];
        float p = 0.f; float4 dq;
        dq = make_float4(xa.x-q0.x, xa.y-q0.y, xa.z-q0.z, xa.w-q0.w); p += dot4(dq,dq);
        dq = make_float4(xb.x-q1.x, xb.y-q1.y, xb.z-q1.z, xb.w-q1.w); p += dot4(dq,dq);
        dq = make_float4(xc.x-q2.x, xc.y-q2.y, xc.z-q2.z, xc.w-q2.w); p += dot4(dq,dq);
        dq = make_float4(xd.x-q3.x, xd.y-q3.y, xd.z-q3.z, xd.w-q3.w); p += dot4(dq,dq);
        dw = wsum(p);
    }

    // ---- P4: z partial (quarter q covers m = q*64 .. +63); attn via shfl ----
    float4 z = make_float4(0.f, 0.f, 0.f, 0.f);
    {
        const float4* zsrc = mem4 + ((q << 6) << 8) + tc;
        auto zrun = [&](float areg) {
            #pragma unroll 4
            for (int i = 0; i < 64; ++i) {
                const float a = __shfl(areg, i, 64);
                float4 v = zsrc[i << 8];
                z.x = fmaf(a, v.x, z.x);
                z.y = fmaf(a, v.y, z.y);
                z.z = fmaf(a, v.z, z.z);
                z.w = fmaf(a, v.w, z.w);
            }
        };
        if      (q == 0) zrun(a0);
        else if (q == 1) zrun(a1);
        else if (q == 2) zrun(a2);
        else             zrun(a3);
    }
    if (q) s_zp[q - 1][tc] = z;
    __syncthreads();                                   // barrier 3
    float drp = 0.f;
    if (q == 0) {
        float4 z1 = s_zp[0][tc], z2 = s_zp[1][tc], z3 = s_zp[2][tc];
        z.x += z1.x + z2.x + z3.x;
        z.y += z1.y + z2.y + z3.y;
        z.z += z1.z + z2.z + z3.z;
        z.w += z1.w + z2.w + z3.w;
        float4 sl = mem4[(idx << 8) + tc];
        float4 d = make_float4(xv.x - sl.x, xv.y - sl.y, xv.z - sl.z, xv.w - sl.w);
        z.x = fmaf(aidx, d.x, z.x);
        z.y = fmaf(aidx, d.y, z.y);
        z.z = fmaf(aidx, d.z, z.z);
        z.w = fmaf(aidx, d.w, z.w);
        float ex = z.x - xv.x, ey = z.y - xv.y, ez = z.z - xv.z, ew = z.w - xv.w;
        drp = ex*ex + ey*ey + ez*ez + ew*ew;
        ((float4*)out)[(size_t)b * C4 + tc] = z;
    }
    {
        float s = wsum(drp);
        if (q == 0 && lane == 0) s_w[wv] = s;          // wv 0..3
    }
    __syncthreads();                                   // barrier 4
    if (t == 0) out[KL_OFF + b] = 0.5f * (dw + s_w[0] + s_w[1] + s_w[2] + s_w[3]);
}

// ---------------- K2: stream. 8192 blocks x 256 thr; block j = (b, 8 rows).
// ALL loads issued before ANY store (no load-behind-store vmcnt stall);
// REGULAR stores (through L2, like the 7 TB/s fill); 32 consecutive blocks
// write one b's 1 MB contiguously.
__global__ __launch_bounds__(256) void tm_stream(const float* __restrict__ x,
                                                 const float* __restrict__ mem,
                                                 const int* __restrict__ idx_ws,
                                                 float* __restrict__ out_um) {
    const int j = blockIdx.x;       // 0..8191
    const int b  = j >> 5;
    const int m0 = (j & 31) << 3;   // 0,8,...,248
    const int t = threadIdx.x;      // column float4 id

    const float4* src = (const float4*)mem + (m0 << 8) + t;
    float4 r0 = src[0 << 8];
    float4 r1 = src[1 << 8];
    float4 r2 = src[2 << 8];
    float4 r3 = src[3 << 8];
    float4 r4 = src[4 << 8];
    float4 r5 = src[5 << 8];
    float4 r6 = src[6 << 8];
    float4 r7 = src[7 << 8];

    const int li = idx_ws[b] - m0;      // blend row if in [0,8); block-uniform
    if (li >= 0 && li < 8) {
        float4 xv = ((const float4*)(x + (size_t)b * C_DIM))[t];
        if (li == 0) r0 = blend9(r0, xv);
        if (li == 1) r1 = blend9(r1, xv);
        if (li == 2) r2 = blend9(r2, xv);
        if (li == 3) r3 = blend9(r3, xv);
        if (li == 4) r4 = blend9(r4, xv);
        if (li == 5) r5 = blend9(r5, xv);
        if (li == 6) r6 = blend9(r6, xv);
        if (li == 7) r7 = blend9(r7, xv);
    }

    float4* dst = (float4*)out_um + ((size_t)b << 16) + (m0 << 8) + t;
    dst[0 << 8] = r0;
    dst[1 << 8] = r1;
    dst[2 << 8] = r2;
    dst[3 << 8] = r3;
    dst[4 << 8] = r4;
    dst[5 << 8] = r5;
    dst[6 << 8] = r6;
    dst[7 << 8] = r7;
}

extern "C" void kernel_launch(void* const* d_in, const int* in_sizes, int n_in,
                              void* d_out, int out_size, void* d_ws, size_t ws_size,
                              hipStream_t stream) {
    const float* x   = (const float*)d_in[0];   // input_encoded [B, C]
    const float* mem = (const float*)d_in[1];   // memory_mean  [M, C]
    float* out = (float*)d_out;
    int* idx_ws = (int*)d_ws;

    tm_pre<<<dim3(B_DIM), dim3(1024), 0, stream>>>(x, mem, out, idx_ws);
    tm_stream<<<dim3(8192), dim3(256), 0, stream>>>(x, mem, idx_ws, out + UM_OFF);
}